// Round 7
// baseline (433.806 us; speedup 1.0000x reference)
//
#include <hip/hip_runtime.h>

// Problem constants
#define BB   16
#define CC   16
#define HH   256
#define WW   256
#define HID  128
#define OUTC 13

typedef short short8 __attribute__((ext_vector_type(8)));
typedef float floatx16 __attribute__((ext_vector_type(16)));

// ---- helpers ----
__device__ __forceinline__ unsigned short f2bf(float x) {
    unsigned int u = __float_as_uint(x);
    u += 0x7fffu + ((u >> 16) & 1u);          // round-to-nearest-even
    return (unsigned short)(u >> 16);
}
__device__ __forceinline__ unsigned int pack2(float lo, float hi) {
    return (unsigned int)f2bf(lo) | ((unsigned int)f2bf(hi) << 16);
}
// packed f32x2 -> bf16x2 (RNE), 1 instr — for h-pack (hot path)
__device__ __forceinline__ unsigned int cvt_pk_bf16(float lo, float hi) {
    unsigned int d;
    asm("v_cvt_pk_bf16_f32 %0, %1, %2" : "=v"(d) : "v"(lo), "v"(hi));
    return d;
}

// ws layout: W1F frags [mtG 0..3][tap 0..8][lane 0..63][8 bf16]  = 36864 B
//            W2F frags [s 0..7][lane 0..63][8 bf16]              =  8192 B at +36864
#define W1F_BYTES 36864
#define W2F_OFF   36864

// ================= prep kernel: bake bf16 weight fragments ==================
__global__ __launch_bounds__(256) void gca_prep(
    const float* __restrict__ w1, const float* __restrict__ w2,
    unsigned char* __restrict__ ws)
{
    const int id = blockIdx.x * 256 + threadIdx.x;   // 2816 total
    const float SX[9] = {-1.f, 0.f, 1.f, -2.f, 0.f, 2.f, -1.f, 0.f, 1.f};
    const float SY[9] = {-1.f, -2.f, -1.f, 0.f, 0.f, 0.f, 1.f, 2.f, 1.f};

    if (id < 2304) {                                  // W1eff frags
        const int mtG  = id / 576;
        const int rem  = id % 576;
        const int tap  = rem / 64;
        const int lane = rem % 64;
        const int p  = lane & 31, hi = lane >> 5;
        const int hid = 32 * mtG + p;
        const float cen = (tap == 4) ? 1.f : 0.f;
        const float sxv = SX[tap], syv = SY[tap];
        const float* wr = w1 + hid * 48;
        unsigned int o[4];
        for (int k = 0; k < 4; ++k) {
            int c0 = 8 * hi + 2 * k;
            float v0 = wr[c0]     * cen + wr[16 + c0]     * sxv + wr[32 + c0]     * syv;
            float v1 = wr[c0 + 1] * cen + wr[16 + c0 + 1] * sxv + wr[32 + c0 + 1] * syv;
            o[k] = (unsigned int)f2bf(v0) | ((unsigned int)f2bf(v1) << 16);
        }
        *(uint4*)(ws + (size_t)id * 16) = make_uint4(o[0], o[1], o[2], o[3]);
    } else if (id < 2816) {                           // W2 (padded outc 13->32) frags
        const int id2 = id - 2304;
        const int s    = id2 / 64;
        const int lane = id2 % 64;
        const int outc = lane & 31, hi = lane >> 5;
        unsigned int o[4];
        for (int k = 0; k < 4; ++k) {
            int hid0 = 16 * s + 8 * hi + 2 * k;
            float v0 = (outc < OUTC) ? w2[outc * HID + hid0]     : 0.f;
            float v1 = (outc < OUTC) ? w2[outc * HID + hid0 + 1] : 0.f;
            o[k] = (unsigned int)f2bf(v0) | ((unsigned int)f2bf(v1) << 16);
        }
        *(uint4*)(ws + W2F_OFF + (size_t)id2 * 16) = make_uint4(o[0], o[1], o[2], o[3]);
    }
}

// ================= main kernel ==============================================
// Block = 128 thr = 2 waves; 8-row x 32-px tile; 4096 blocks.
// OCCUPANCY MODEL (fits rounds 0-6): gfx950 wave residency steps at unified
// VGPR+AGPR totals {64,128,256}. All prior non-spill kernels sat at
// 100+48=148 -> 256-class -> 2 waves/SIMD -> measured occ ~20%. This version
// shrinks demand (h in LDS, no hrun regs, no shuffles, no cbuf) and forces
// the 128-class via __launch_bounds__(128,4) -> 4 waves/SIMD target.
// Per row: both waves GEMM1 their hid-half -> pack h -> LDS -> barrier ->
// BOTH waves full-K GEMM2 (dup MFMA is cheap at 12% util), parity-split
// residual C-init + stores. No partial-sum exchange.
// TRIPWIRE: WRITE_SIZE must be exactly 65536 KB (no spills).
#define TILE_DW 3400                       // 10 rows x 34 cols x 10 dw/px
#define H_DW    2048                       // h[krow 32][px 32] uint2 = 8 KB
#define LDS_DW  (TILE_DW + H_DW)           // 5448 dw = 21792 B -> 7 blocks/CU

__global__ __launch_bounds__(128, 4) void gca_main(
    const float* __restrict__ in,
    const float* __restrict__ b1,
    const unsigned char* __restrict__ ws,
    float* __restrict__ out)
{
    __shared__ unsigned int lds[LDS_DW];

    const int tid  = threadIdx.x;
    const int hw   = tid >> 6;     // hid-half for GEMM1; channel parity for output
    const int lane = tid & 63;
    const int p    = lane & 31;    // pixel-in-group / m-index
    const int hi   = lane >> 5;    // k-half selector

    const int bI = blockIdx.x >> 8;          // image
    const int rm = blockIdx.x & 255;
    const int y0 = (rm >> 3) << 3;           // 8-row span
    const int x0 = (rm & 7)  << 5;           // 32-px span

    const float* inb  = in  + ((size_t)bI << 20);
    float*       outb = out + ((size_t)bI << 20);

    // ---- stage halo tile (rows y0-1..y0+8, cols x0-1..x0+32), f32 -> bf16 ----
    {
        const int g = tid >> 5, l = tid & 31;
        const float* cp0 = inb + ((size_t)(2 * g) << 16);      // channels 2g, 2g+1
        const int xA = (x0 + l - 1) & 255;
        const int xB = (x0 + l + 31) & 255;                    // cols 32,33 (l<2)
        const int ldsA = l * 10 + g;
        const int ldsB = (l + 32) * 10 + g;
        const bool doB = (l < 2);
        for (int rw = 0; rw < 10; ++rw) {
            const int yo = ((y0 + rw - 1) & 255) << 8;
            float a0 = cp0[yo + xA];
            float a1 = cp0[yo + xA + (1 << 16)];
            float b0 = cp0[yo + xA + (8 << 16)];               // channels 2g+8, 2g+9
            float b1v = cp0[yo + xA + (9 << 16)];
            lds[rw * 340 + ldsA]     = pack2(a0, a1);
            lds[rw * 340 + ldsA + 4] = pack2(b0, b1v);
            if (doB) {
                float c0 = cp0[yo + xB];
                float c1 = cp0[yo + xB + (1 << 16)];
                float d0 = cp0[yo + xB + (8 << 16)];
                float d1 = cp0[yo + xB + (9 << 16)];
                lds[rw * 340 + ldsB]     = pack2(c0, c1);
                lds[rw * 340 + ldsB + 4] = pack2(d0, d1);
            }
        }
    }
    __syncthreads();

    const unsigned char* w1f = ws + ((size_t)(2 * hw) * 9) * 64 * 16; // mtG = 2hw+m
    const unsigned char* w2f = ws + W2F_OFF;                          // full K table

    // h LDS addressing: dw = TILE_DW + krow*64 + 2p.
    // write krow = 16hw + 8m + 2rr + hi  (k = 4*krow + j, j=0..3 packed)
    // read  krow = 4sp + 2hi (+1)        (b2 k = 16sp+8hi+{0..7})
    const int hwb = TILE_DW + (16 * hw + hi) * 64 + 2 * p;
    const int hrb = TILE_DW + hi * 128 + 2 * p;

#pragma unroll 1
    for (int t = 0; t < 8; ++t) {
        const int row   = y0 + t;
        const int ibase = (row << 8) + x0 + p;

        // ---- residual preload, own-parity channels (r = 2j+hw) ----
        float rs[8];
#pragma unroll
        for (int j = 0; j < 8; ++j) {
            const int r  = 2 * j + hw;
            const int oc = (r & 3) + 8 * (r >> 2) + 4 * hi;
            rs[j] = (oc < OUTC) ? inb[ibase + ((3 + oc) << 16)] : 0.f;
        }

        // ---- acc1 init = b1 (pre-relu bias) ----
        floatx16 acc1[2];
#pragma unroll
        for (int m = 0; m < 2; ++m) {
            const int hb = 64 * hw + 32 * m + 4 * hi;
#pragma unroll
            for (int rr = 0; rr < 4; ++rr) {
                float4 bv = *(const float4*)(b1 + hb + 8 * rr);
                acc1[m][4 * rr + 0] = bv.x;
                acc1[m][4 * rr + 1] = bv.y;
                acc1[m][4 * rr + 2] = bv.z;
                acc1[m][4 * rr + 3] = bv.w;
            }
        }

        // ---- GEMM1: 9 taps (K=16 each), this wave's 64 hids ----
#pragma unroll
        for (int tap = 0; tap < 9; ++tap) {
            const int tr  = t + tap / 3;
            const int col = p + tap % 3;
            const int dwo = (tr * 34 + col) * 10 + 4 * hi;
            union { unsigned int u[4]; short8 s; } bfr;
            uint2 lo2 = *(const uint2*)&lds[dwo];
            uint2 hi2 = *(const uint2*)&lds[dwo + 2];
            bfr.u[0] = lo2.x; bfr.u[1] = lo2.y; bfr.u[2] = hi2.x; bfr.u[3] = hi2.y;
#pragma unroll
            for (int m = 0; m < 2; ++m) {
                short8 af = *(const short8*)(w1f + (size_t)((m * 9 + tap) * 64 + lane) * 16);
                acc1[m] = __builtin_amdgcn_mfma_f32_32x32x16_bf16(af, bfr.s, acc1[m], 0, 0, 0);
            }
        }

        // ---- relu + pack h -> LDS (kills hrun regs and all shuffles) ----
#pragma unroll
        for (int m = 0; m < 2; ++m)
#pragma unroll
            for (int rr = 0; rr < 4; ++rr) {
                float h0 = fmaxf(acc1[m][4 * rr + 0], 0.f);
                float h1 = fmaxf(acc1[m][4 * rr + 1], 0.f);
                float h2 = fmaxf(acc1[m][4 * rr + 2], 0.f);
                float h3 = fmaxf(acc1[m][4 * rr + 3], 0.f);
                uint2 v;
                v.x = cvt_pk_bf16(h0, h1);
                v.y = cvt_pk_bf16(h2, h3);
                *(uint2*)&lds[hwb + (8 * m + 2 * rr) * 64] = v;
            }
        __syncthreads();                       // h complete

        // ---- acc2 C-init = residual on own-parity regs ----
        floatx16 acc2 = {};
        if (hw == 0) {
            acc2[0]  = rs[0]; acc2[2]  = rs[1]; acc2[4]  = rs[2]; acc2[6]  = rs[3];
            acc2[8]  = rs[4]; acc2[10] = rs[5]; acc2[12] = rs[6]; acc2[14] = rs[7];
        } else {
            acc2[1]  = rs[0]; acc2[3]  = rs[1]; acc2[5]  = rs[2]; acc2[7]  = rs[3];
            acc2[9]  = rs[4]; acc2[11] = rs[5]; acc2[13] = rs[6]; acc2[15] = rs[7];
        }

        // ---- GEMM2 full K=128 (both waves; b2 frags straight from LDS) ----
#pragma unroll
        for (int sp = 0; sp < 8; ++sp) {
            uint2 u0 = *(const uint2*)&lds[hrb + sp * 256];
            uint2 u1 = *(const uint2*)&lds[hrb + sp * 256 + 64];
            union { unsigned int u[4]; short8 s; } b2;
            b2.u[0] = u0.x; b2.u[1] = u0.y; b2.u[2] = u1.x; b2.u[3] = u1.y;
            short8 a2 = *(const short8*)(w2f + (size_t)(sp * 64 + lane) * 16);
            acc2 = __builtin_amdgcn_mfma_f32_32x32x16_bf16(a2, b2.s, acc2, 0, 0, 0);
        }

        // ---- store own-parity channels (residual already C-init'ed) ----
        if (hw == 0) {
#pragma unroll
            for (int j = 0; j < 8; ++j) {
                const int r  = 2 * j;
                const int oc = (r & 3) + 8 * (r >> 2) + 4 * hi;
                if (oc < OUTC)
                    outb[ibase + ((3 + oc) << 16)] = acc2[2 * j];
            }
        } else {
#pragma unroll
            for (int j = 0; j < 8; ++j) {
                const int r  = 2 * j + 1;
                const int oc = (r & 3) + 8 * (r >> 2) + 4 * hi;
                if (oc < OUTC)
                    outb[ibase + ((3 + oc) << 16)] = acc2[2 * j + 1];
            }
        }

        // ---- passthrough channels 0..2 for this row (48 px per wave) ----
        if (lane < 48) {
            const int e  = 48 * hw + lane;
            const int c  = e >> 5;
            const int px = e & 31;
            const int idx = (c << 16) + (row << 8) + x0 + px;
            outb[idx] = inb[idx];
        }

        __syncthreads();                       // protect h reuse next row
    }
}

extern "C" void kernel_launch(void* const* d_in, const int* in_sizes, int n_in,
                              void* d_out, int out_size, void* d_ws, size_t ws_size,
                              hipStream_t stream) {
    const float* x  = (const float*)d_in[0];
    const float* w1 = (const float*)d_in[1];
    const float* b1 = (const float*)d_in[2];
    const float* w2 = (const float*)d_in[3];
    float* out = (float*)d_out;
    unsigned char* ws = (unsigned char*)d_ws;

    hipLaunchKernelGGL(gca_prep, dim3(11), dim3(256), 0, stream, w1, w2, ws);
    hipLaunchKernelGGL(gca_main, dim3(4096), dim3(128), 0, stream, x, b1, ws, out);
}

// Round 9
// 223.233 us; speedup vs baseline: 1.9433x; 1.9433x over previous
//
#include <hip/hip_runtime.h>

// Problem constants
#define BB   16
#define CC   16
#define HH   256
#define WW   256
#define HID  128
#define OUTC 13

typedef short short8 __attribute__((ext_vector_type(8)));
typedef float floatx16 __attribute__((ext_vector_type(16)));
typedef float floatx4 __attribute__((ext_vector_type(4)));

// ---- helpers ----
__device__ __forceinline__ unsigned short f2bf(float x) {
    unsigned int u = __float_as_uint(x);
    u += 0x7fffu + ((u >> 16) & 1u);          // round-to-nearest-even
    return (unsigned short)(u >> 16);
}
__device__ __forceinline__ unsigned int pack2(float lo, float hi) {
    return (unsigned int)f2bf(lo) | ((unsigned int)f2bf(hi) << 16);
}
// packed f32x2 -> bf16x2 (RNE), 1 instr — hot path
__device__ __forceinline__ unsigned int cvt_pk_bf16(float lo, float hi) {
    unsigned int d;
    asm("v_cvt_pk_bf16_f32 %0, %1, %2" : "=v"(d) : "v"(lo), "v"(hi));
    return d;
}

// ws layout: W1F frags [mtG 0..3][tap 0..8][lane 0..63][8 bf16]  = 36864 B
//            W2F frags [s 0..7][lane 0..63][8 bf16]              =  8192 B at +36864
#define W1F_BYTES 36864
#define W2F_OFF   36864

// ================= prep kernel: bake bf16 weight fragments ==================
__global__ __launch_bounds__(256) void gca_prep(
    const float* __restrict__ w1, const float* __restrict__ w2,
    unsigned char* __restrict__ ws)
{
    const int id = blockIdx.x * 256 + threadIdx.x;   // 2816 total
    const float SX[9] = {-1.f, 0.f, 1.f, -2.f, 0.f, 2.f, -1.f, 0.f, 1.f};
    const float SY[9] = {-1.f, -2.f, -1.f, 0.f, 0.f, 0.f, 1.f, 2.f, 1.f};

    if (id < 2304) {                                  // W1eff frags
        const int mtG  = id / 576;
        const int rem  = id % 576;
        const int tap  = rem / 64;
        const int lane = rem % 64;
        const int p  = lane & 31, hi = lane >> 5;
        const int hid = 32 * mtG + p;
        const float cen = (tap == 4) ? 1.f : 0.f;
        const float sxv = SX[tap], syv = SY[tap];
        const float* wr = w1 + hid * 48;
        unsigned int o[4];
        for (int k = 0; k < 4; ++k) {
            int c0 = 8 * hi + 2 * k;
            float v0 = wr[c0]     * cen + wr[16 + c0]     * sxv + wr[32 + c0]     * syv;
            float v1 = wr[c0 + 1] * cen + wr[16 + c0 + 1] * sxv + wr[32 + c0 + 1] * syv;
            o[k] = (unsigned int)f2bf(v0) | ((unsigned int)f2bf(v1) << 16);
        }
        *(uint4*)(ws + (size_t)id * 16) = make_uint4(o[0], o[1], o[2], o[3]);
    } else if (id < 2816) {                           // W2 (padded outc 13->32) frags
        const int id2 = id - 2304;
        const int s    = id2 / 64;
        const int lane = id2 % 64;
        const int outc = lane & 31, hi = lane >> 5;
        unsigned int o[4];
        for (int k = 0; k < 4; ++k) {
            int hid0 = 16 * s + 8 * hi + 2 * k;
            float v0 = (outc < OUTC) ? w2[outc * HID + hid0]     : 0.f;
            float v1 = (outc < OUTC) ? w2[outc * HID + hid0 + 1] : 0.f;
            o[k] = (unsigned int)f2bf(v0) | ((unsigned int)f2bf(v1) << 16);
        }
        *(uint4*)(ws + W2F_OFF + (size_t)id2 * 16) = make_uint4(o[0], o[1], o[2], o[3]);
    }
}

// ================= main kernel ==============================================
// Block = 256 thr = 4 waves; 8-row x 32-px tile; 4096 blocks.
// QUARTER-SPLIT: wave w owns hid quarter mtG=w in GEMM1 -> acc1 is ONE
// floatx16 (16 regs, vs 32 in all prior versions). Fixed accumulators now
// 32 regs total; demand fits the 128-class WITHOUT spilling (goal).
// Per row t: each wave GEMM1s its quarter (9 MFMA) -> relu-pack h quarter ->
// LDS hbuf[t&1] -> barrier -> ALL waves full-K=128 GEMM2 (8 MFMA, dup x4 is
// free at <10% MfmaUtil) -> 4-way channel-split store with epilogue residual
// reload (no rs[] live across GEMM1). Single barrier/iter via h ping-pong.
// REGISTER MODEL (fits rounds 0-7): waves/SIMD = floor(512/round64(demand)),
// demand = unified VGPR+AGPR. 148->class192->2 w/SIMD (occ~20%, rounds 0,6);
// forced 128-cap with demand>128 -> scratch spills (FETCH x5, rounds 2,7).
// TRIPWIRE: WRITE_SIZE must be exactly 65536 KB (no spills).
#define TILE_DW 3400                       // 10 rows x 34 cols x 10 dw/px
#define HB_DW   2048                       // h[krow 32][px 32] uint2 = 8 KB
#define LDS_DW  (TILE_DW + 2 * HB_DW)      // 7496 dw = 29984 B -> 5 blocks/CU LDS

__global__ __launch_bounds__(256, 4) void gca_main(
    const float* __restrict__ in,
    const float* __restrict__ b1,
    const unsigned char* __restrict__ ws,
    float* __restrict__ out)
{
    __shared__ unsigned int lds[LDS_DW];

    const int tid  = threadIdx.x;
    const int w    = tid >> 6;     // wave = hid quarter (mtG) AND channel split
    const int lane = tid & 63;
    const int p    = lane & 31;    // pixel-in-group / m-index
    const int hi   = lane >> 5;    // k-half selector

    const int bI = blockIdx.x >> 8;          // image
    const int rm = blockIdx.x & 255;
    const int y0 = (rm >> 3) << 3;           // 8-row span
    const int x0 = (rm & 7)  << 5;           // 32-px span

    const float* inb  = in  + ((size_t)bI << 20);
    float*       outb = out + ((size_t)bI << 20);

    // ---- prologue: passthrough channels 0..2 (8 rows x 32 px, float4) ----
    if (tid < 192) {
        const int c  = tid >> 6;
        const int rem = tid & 63;
        const int rw = rem >> 3, q = rem & 7;
        const int idx = (c << 16) + ((y0 + rw) << 8) + x0 + (q << 2);
        *(floatx4*)(outb + idx) = *(const floatx4*)(inb + idx);
    }

    // ---- stage halo tile (rows y0-1..y0+8, cols x0-1..x0+32), f32 -> bf16 ----
    // g = tid>>5 = channel pair (2g,2g+1); l = tid&31 = column. No div/mod.
    {
        const int g = tid >> 5, l = tid & 31;
        const float* cp = inb + ((size_t)(2 * g) << 16);
        const int xA = (x0 + l - 1) & 255;
        const int xB = (x0 + l + 31) & 255;      // cols 32,33 (l<2 only)
        const int ldsA = l * 10 + g;
        const int ldsB = (l + 32) * 10 + g;
        const bool doB = (l < 2);
        for (int rw = 0; rw < 10; ++rw) {
            const int yo = ((y0 + rw - 1) & 255) << 8;
            float a0 = cp[yo + xA], a1 = cp[yo + xA + 65536];
            lds[rw * 340 + ldsA] = pack2(a0, a1);
            if (doB) {
                float c0 = cp[yo + xB], c1 = cp[yo + xB + 65536];
                lds[rw * 340 + ldsB] = pack2(c0, c1);
            }
        }
    }
    __syncthreads();

    const unsigned char* w1f = ws + (size_t)(w * 9) * 64 * 16;   // this wave's mtG
    const unsigned char* w2f = ws + W2F_OFF;                     // full K table

    // h LDS addressing (dw = base + krow*64 + 2p):
    //   write: krow = 8w + 2rr + hi   (hid = 32w + 8rr + 4hi + j, j=0..3 packed)
    //   read : krow = 4sp + 2hi (+1)  (b2 k = 16sp + 8hi + {0..7})
    const int hwo = (8 * w + hi) * 64 + 2 * p;      // + rr*128
    const int hro = hi * 128 + 2 * p;               // + sp*256 (+64)

    // epilogue channel constants: r = 4q+w -> oc = w + 8q + 4hi (q=0,1)
    const int oc0 = w + 4 * hi;                     // always < 13
    const int oc1 = oc0 + 8;                        // valid iff < 13
    const int off0 = (3 + oc0) << 16;
    const int off1 = (3 + oc1) << 16;
    const bool v1 = (oc1 < OUTC);

#pragma unroll 1
    for (int t = 0; t < 8; ++t) {
        const int row   = y0 + t;
        const int ibase = (row << 8) + x0 + p;
        const int hb    = TILE_DW + (t & 1) * HB_DW;

        // ---- acc1 init = b1 (pre-relu bias) for this wave's 32 hids ----
        floatx16 acc1;
        {
            const int hbase = 32 * w + 4 * hi;
#pragma unroll
            for (int rr = 0; rr < 4; ++rr) {
                float4 bv = *(const float4*)(b1 + hbase + 8 * rr);
                acc1[4 * rr + 0] = bv.x;
                acc1[4 * rr + 1] = bv.y;
                acc1[4 * rr + 2] = bv.z;
                acc1[4 * rr + 3] = bv.w;
            }
        }

        // ---- GEMM1: 9 taps (K=16 each), one m-tile ----
#pragma unroll
        for (int tap = 0; tap < 9; ++tap) {
            const int tr  = t + tap / 3;
            const int col = p + tap % 3;
            const int dwo = (tr * 34 + col) * 10 + 4 * hi;
            union { unsigned int u[4]; short8 s; } bfr;
            uint2 lo2 = *(const uint2*)&lds[dwo];
            uint2 hi2 = *(const uint2*)&lds[dwo + 2];
            bfr.u[0] = lo2.x; bfr.u[1] = lo2.y; bfr.u[2] = hi2.x; bfr.u[3] = hi2.y;
            short8 af = *(const short8*)(w1f + (size_t)(tap * 64 + lane) * 16);
            acc1 = __builtin_amdgcn_mfma_f32_32x32x16_bf16(af, bfr.s, acc1, 0, 0, 0);
        }

        // ---- relu + pack this quarter's h -> LDS hbuf[t&1] ----
#pragma unroll
        for (int rr = 0; rr < 4; ++rr) {
            float h0 = fmaxf(acc1[4 * rr + 0], 0.f);
            float h1 = fmaxf(acc1[4 * rr + 1], 0.f);
            float h2 = fmaxf(acc1[4 * rr + 2], 0.f);
            float h3 = fmaxf(acc1[4 * rr + 3], 0.f);
            uint2 v;
            v.x = cvt_pk_bf16(h0, h1);
            v.y = cvt_pk_bf16(h2, h3);
            *(uint2*)&lds[hb + hwo + rr * 128] = v;
        }
        __syncthreads();                       // h complete (single barrier/iter)

        // ---- GEMM2 full K=128 (every wave; b2 straight from LDS) ----
        floatx16 acc2 = {};
#pragma unroll
        for (int sp = 0; sp < 8; ++sp) {
            uint2 u0 = *(const uint2*)&lds[hb + hro + sp * 256];
            uint2 u1 = *(const uint2*)&lds[hb + hro + sp * 256 + 64];
            union { unsigned int u[4]; short8 s; } b2;
            b2.u[0] = u0.x; b2.u[1] = u0.y; b2.u[2] = u1.x; b2.u[3] = u1.y;
            short8 a2 = *(const short8*)(w2f + (size_t)(sp * 64 + lane) * 16);
            acc2 = __builtin_amdgcn_mfma_f32_32x32x16_bf16(a2, b2.s, acc2, 0, 0, 0);
        }

        // ---- 4-way channel-split store, residual reloaded at epilogue ----
        // r = 4q + w  ->  oc = w + 8q + 4hi ; q=0 always valid, q=1 if oc1<13
        {
            const int i0 = ibase + off0;
            float r0 = inb[i0];
            outb[i0] = r0 + acc2[w];           // q=0: acc2[4*0+w]
            if (v1) {
                const int i1 = ibase + off1;
                float r1 = inb[i1];
                outb[i1] = r1 + acc2[4 + w];   // q=1: acc2[4*1+w]
            }
        }
        // (no trailing barrier: next iter writes the OTHER h buffer; a wave's
        //  own LDS reads of hb complete before its next-iter writes by
        //  program order + lgkmcnt; cross-wave reuse of this buffer happens
        //  only after the NEXT barrier.)
    }
}

extern "C" void kernel_launch(void* const* d_in, const int* in_sizes, int n_in,
                              void* d_out, int out_size, void* d_ws, size_t ws_size,
                              hipStream_t stream) {
    const float* x  = (const float*)d_in[0];
    const float* w1 = (const float*)d_in[1];
    const float* b1 = (const float*)d_in[2];
    const float* w2 = (const float*)d_in[3];
    float* out = (float*)d_out;
    unsigned char* ws = (unsigned char*)d_ws;

    hipLaunchKernelGGL(gca_prep, dim3(11), dim3(256), 0, stream, w1, w2, ws);
    hipLaunchKernelGGL(gca_main, dim3(4096), dim3(256), 0, stream, x, b1, ws, out);
}